// Round 8
// baseline (76.757 us; speedup 1.0000x reference)
//
#include <hip/hip_runtime.h>
#include <math.h>

#define G 10                 // grid cells per dim (cell = 1.0 unit)
#define NCELL (G*G*G)        // 1000
#define INV_CS 1.0f          // G / 10.0
#define CS 1.0f              // 10.0 / G
#define KNN 3
#define BIGF 3.402823466e+38f

#define BLOCK 1024
#define NWAVE (BLOCK / 64)                     // 16
#define SPLIT 8                                // lanes cooperating per point
#define PTS_PER_BLOCK (BLOCK / SPLIT)          // 128 points searched per block
#define SEG 4096                               // points per segment
#define PPT (SEG / BLOCK)                      // staging points per thread = 4

#define KEYMASK 0xFFFFF000u                    // 20-bit d2 | 12-bit id
#define BIGK    0xFFFFFFFFu

__device__ __forceinline__ int cell_of(float x, float y, float z) {
    int cx = (int)(x * INV_CS); cx = cx < 0 ? 0 : (cx > G-1 ? G-1 : cx);
    int cy = (int)(y * INV_CS); cy = cy < 0 ? 0 : (cy > G-1 ? G-1 : cy);
    int cz = (int)(z * INV_CS); cz = cz < 0 ? 0 : (cz > G-1 ? G-1 : cz);
    return (cx * G + cy) * G + cz;
}

// branchless top-3 (ascending) on u32 keys: 5 min/max
__device__ __forceinline__ void pk_insert(unsigned k, unsigned& m0, unsigned& m1, unsigned& m2) {
    const unsigned lo0 = min(m0, k);
    const unsigned hi0 = max(m0, k);
    m0 = lo0;
    const unsigned lo1 = min(m1, hi0);
    const unsigned hi1 = max(m1, hi0);
    m1 = lo1;
    m2 = min(m2, hi1);
}

// One kernel: each block redundantly counting-sorts its whole segment into
// LDS (cell order), then does exact 3-NN + loss for its 128 original points.
// G=10: ~4.1 pts/cell -> 27-cell box ~ 110 candidates (vs 216 at G=8); the
// R-expansion guard keeps exactness (expansion prob ~1e-5, corner points).
__global__ __launch_bounds__(BLOCK) void fused_knn_loss(
    const float* __restrict__ pred,
    const float* __restrict__ coord,
    const float* __restrict__ target,
    float* __restrict__ out,
    int seg, int bps,            // bps = blocks per segment = seg / PTS_PER_BLOCK
    float inv_total)
{
    __shared__ float2 sxy[SEG];                 // 32 KB
    __shared__ float  sz[SEG];                  // 16 KB
    __shared__ unsigned short sid[SEG];         //  8 KB
    __shared__ unsigned short csl[NCELL + 1];   //  2 KB (values <= 4096)
    __shared__ int   hist[NCELL];               //  4 KB (then cursor)
    __shared__ int   wsum[NWAVE];
    __shared__ float wred[NWAVE];
    // total ~62.2 KB (< 64 KB static-LDS line)

    const int tid = threadIdx.x;
    const int s   = blockIdx.x / bps;
    const long segbase = (long)s * seg;

    // ---- phase 1: load my 4 staging points, histogram cells ----
    if (tid < NCELL) hist[tid] = 0;
    __syncthreads();

    float px[PPT], py[PPT], pz[PPT];
    int   pc[PPT];
    #pragma unroll
    for (int k = 0; k < PPT; ++k) {
        const int p = tid + k * BLOCK;
        px[k] = coord[(segbase + p)*3 + 0];
        py[k] = coord[(segbase + p)*3 + 1];
        pz[k] = coord[(segbase + p)*3 + 2];
        pc[k] = cell_of(px[k], py[k], pz[k]);
        atomicAdd(&hist[pc[k]], 1);
    }
    __syncthreads();

    // ---- phase 2: exclusive scan of 1000 cell counts (wave-shuffle) ----
    int own = 0;
    if (tid < NCELL) own = hist[tid];
    int v = own;                                 // lanes >= NCELL carry 0
    #pragma unroll
    for (int off = 1; off < 64; off <<= 1) {
        const int t = __shfl_up(v, off);
        if ((tid & 63) >= off) v += t;
    }
    if ((tid & 63) == 63) wsum[tid >> 6] = v;    // unconditional: wave 15 is partial
    __syncthreads();
    if (tid < 64) {                              // wave 0 scans the 16 wave sums
        int w = (tid < NWAVE) ? wsum[tid] : 0;
        #pragma unroll
        for (int off = 1; off < NWAVE; off <<= 1) {
            const int t = __shfl_up(w, off);
            if (tid >= off) w += t;
        }
        if (tid < NWAVE) wsum[tid] = w;
    }
    __syncthreads();
    if (tid < NCELL) {
        const int wid  = tid >> 6;
        const int incl = v + (wid ? wsum[wid - 1] : 0);
        const int excl = incl - own;
        csl[tid] = (unsigned short)excl;
        if (tid == NCELL - 1) csl[NCELL] = (unsigned short)incl;  // == seg
        hist[tid] = excl;                        // becomes scatter cursor
    }
    __syncthreads();

    // ---- phase 3: scatter into cell-sorted LDS ----
    #pragma unroll
    for (int k = 0; k < PPT; ++k) {
        const int slot = atomicAdd(&hist[pc[k]], 1);
        sxy[slot] = make_float2(px[k], py[k]);
        sz[slot]  = pz[k];
        sid[slot] = (unsigned short)(tid + k * BLOCK);
    }
    __syncthreads();

    // ---- phase 4: exact 3-NN for my 128 ORIGINAL points (8 lanes/point) ----
    const int sub   = tid & (SPLIT - 1);
    const int grp   = tid >> 3;
    const int jloc  = (blockIdx.x % bps) * PTS_PER_BLOCK + grp;  // original local idx
    const float mx = coord[(segbase + jloc)*3 + 0];              // 8-lane broadcast
    const float my = coord[(segbase + jloc)*3 + 1];
    const float mz = coord[(segbase + jloc)*3 + 2];
    int cx = (int)(mx * INV_CS); cx = cx > G-1 ? G-1 : cx;
    int cy = (int)(my * INV_CS); cy = cy > G-1 ? G-1 : cy;
    int cz = (int)(mz * INV_CS); cz = cz > G-1 ? G-1 : cz;

    unsigned m0, m1, m2;
    int R = 1;
    for (;;) {
        m0 = BIGK; m1 = BIGK; m2 = BIGK;
        const int x0 = max(cx - R, 0), x1 = min(cx + R, G-1);
        const int y0 = max(cy - R, 0), y1 = min(cy + R, G-1);
        const int z0 = max(cz - R, 0), z1 = min(cz + R, G-1);
        for (int gx = x0; gx <= x1; ++gx) {
            for (int gy = y0; gy <= y1; ++gy) {
                const int base = (gx * G + gy) * G;
                const int q0 = csl[base + z0];
                const int q1 = csl[base + z1 + 1];
                for (int q = q0 + sub; q < q1; q += SPLIT) {
                    const float2 xy = sxy[q];
                    const float  zz = sz[q];
                    const unsigned id = sid[q];
                    const float dx = mx - xy.x;
                    const float dy = my - xy.y;
                    const float dz = mz - zz;
                    const float d2 = fmaf(dx, dx, fmaf(dy, dy, dz * dz));
                    unsigned key = (__float_as_uint(d2) & KEYMASK) | id;
                    if ((int)id == jloc) key = BIGK;           // exclude self
                    pk_insert(key, m0, m1, m2);
                }
            }
        }
        // butterfly merge across the 8 lanes of this point
        #pragma unroll
        for (int mask = 1; mask < SPLIT; mask <<= 1) {
            const unsigned o0 = __shfl_xor(m0, mask);
            const unsigned o1 = __shfl_xor(m1, mask);
            const unsigned o2 = __shfl_xor(m2, mask);
            pk_insert(o0, m0, m1, m2);
            pk_insert(o1, m0, m1, m2);
            pk_insert(o2, m0, m1, m2);
        }
        // guard: truncated d3 underestimates true d3 by <= 2^-11 rel; 0.999
        // safety factor keeps the box-coverage proof valid.
        const float d3 = __uint_as_float(m2 & KEYMASK);
        const float g = (float)R * CS;
        if (d3 <= g * g * 0.999f || R >= G) break;
        ++R;   // exactness guard failed (rare corner case) — widen box
    }

    // ---- epilogue: lanes sub=0,1,2 each handle one neighbor ----
    float loss = 0.0f;
    if (sub < KNN) {
        const unsigned mk = (sub == 0) ? m0 : (sub == 1) ? m1 : m2;
        const int nk = (int)(mk & 0xFFFu);
        const long gp = segbase + jloc;
        const float ppx = pred[gp*3+0], ppy = pred[gp*3+1], ppz = pred[gp*3+2];
        const float inp = sqrtf(ppx*ppx + ppy*ppy + ppz*ppz + 1e-8f) + 1e-10f;
        const float qx = ppx / inp, qy = ppy / inp, qz = ppz / inp;
        const float tx = target[gp*3+0], ty = target[gp*3+1], tz = target[gp*3+2];

        const long gn = segbase + nk;
        const float nx = pred[gn*3+0], ny = pred[gn*3+1], nz = pred[gn*3+2];
        const float ninp = sqrtf(nx*nx + ny*ny + nz*nz + 1e-8f) + 1e-10f;
        float sim = fabsf((nx*qx + ny*qy + nz*qz) / ninp);
        sim = fminf(sim, 1.0f);
        const float ux = target[gn*3+0], uy = target[gn*3+1], uz = target[gn*3+2];
        float tsim = fabsf(ux*tx + uy*ty + uz*tz);
        tsim = fminf(tsim, 1.0f);
        const float diff = sim - tsim;
        loss = diff * diff;
    }

    // wave reduce -> LDS -> one atomic per block
    #pragma unroll
    for (int off = 32; off > 0; off >>= 1)
        loss += __shfl_down(loss, off);
    if ((tid & 63) == 0) wred[tid >> 6] = loss;
    __syncthreads();
    if (tid == 0) {
        float ssum = 0.0f;
        #pragma unroll
        for (int w = 0; w < NWAVE; ++w) ssum += wred[w];
        atomicAdd(out, ssum * inv_total);
    }
}

extern "C" void kernel_launch(void* const* d_in, const int* in_sizes, int n_in,
                              void* d_out, int out_size, void* d_ws, size_t ws_size,
                              hipStream_t stream) {
    const float* pred   = (const float*)d_in[0];
    const float* coord  = (const float*)d_in[1];
    const float* target = (const float*)d_in[2];
    float* out = (float*)d_out;

    const int N    = in_sizes[0] / 3;
    const int nseg = in_sizes[3];
    const int seg  = N / nseg;                  // 4096
    const int bps  = seg / PTS_PER_BLOCK;       // 32

    hipMemsetAsync(out, 0, sizeof(float), stream);

    const float inv_total = 1.0f / ((float)nseg * (float)seg * (float)KNN);
    fused_knn_loss<<<N / PTS_PER_BLOCK, BLOCK, 0, stream>>>(
        pred, coord, target, out, seg, bps, inv_total);
}

// Round 9
// 72.923 us; speedup vs baseline: 1.0526x; 1.0526x over previous
//
#include <hip/hip_runtime.h>
#include <math.h>

#define G 8                  // grid cells per dim (cell = 1.25 units)
#define NCELL (G*G*G)        // 512
#define INV_CS 0.8f          // G / 10.0
#define CS 1.25f             // 10.0 / G
#define KNN 3

#define BLOCK 1024
#define NWAVE (BLOCK / 64)                     // 16
#define SPLIT 8                                // lanes cooperating per point
#define PTS_PER_BLOCK (BLOCK / SPLIT)          // 128 points searched per block
#define SEG 4096                               // points per segment
#define PPT (SEG / BLOCK)                      // staging points per thread = 4

#define KEYMASK 0xFFFFF000u                    // 20-bit d2 | 12-bit slot
#define BIGK    0xFFFFFFFFu

__device__ __forceinline__ int cell_of(float x, float y, float z) {
    int cx = (int)(x * INV_CS); cx = cx < 0 ? 0 : (cx > G-1 ? G-1 : cx);
    int cy = (int)(y * INV_CS); cy = cy < 0 ? 0 : (cy > G-1 ? G-1 : cy);
    int cz = (int)(z * INV_CS); cz = cz < 0 ? 0 : (cz > G-1 ? G-1 : cz);
    return (cx << 6) | (cy << 3) | cz;
}

// branchless top-4 (ascending) on u32 keys: 7 min/max
__device__ __forceinline__ void pk_insert4(unsigned k, unsigned& m0, unsigned& m1,
                                           unsigned& m2, unsigned& m3) {
    const unsigned lo0 = min(m0, k), hi0 = max(m0, k); m0 = lo0;
    const unsigned lo1 = min(m1, hi0), hi1 = max(m1, hi0); m1 = lo1;
    const unsigned lo2 = min(m2, hi1), hi2 = max(m2, hi1); m2 = lo2;
    m3 = min(m3, hi2);
}

// branchless top-3 insert (for the cross-lane merge)
__device__ __forceinline__ void pk_insert(unsigned k, unsigned& m0, unsigned& m1, unsigned& m2) {
    const unsigned lo0 = min(m0, k), hi0 = max(m0, k); m0 = lo0;
    const unsigned lo1 = min(m1, hi0), hi1 = max(m1, hi0); m1 = lo1;
    m2 = min(m2, hi1);
}

// One kernel: each block redundantly counting-sorts its whole segment into
// LDS (cell order), then does exact 3-NN + loss for its 128 original points.
// Self-exclusion trick: self candidate has d2 == +0.0 exactly, so its key
// (d2trunc|slot) < 4096 — keep top-4 during the scan, shift self out after.
// This removes the per-candidate sid read (3 LDS ops -> 2) and the id compare.
__global__ __launch_bounds__(BLOCK) void fused_knn_loss(
    const float* __restrict__ pred,
    const float* __restrict__ coord,
    const float* __restrict__ target,
    float* __restrict__ out,
    int seg, int bps,            // bps = blocks per segment = seg / PTS_PER_BLOCK
    float inv_total)
{
    __shared__ float2 sxy[SEG];                 // 32 KB
    __shared__ float  sz[SEG];                  // 16 KB
    __shared__ unsigned short sid[SEG];         //  8 KB (epilogue lookup only)
    __shared__ int   csl[NCELL + 1];            //  2 KB
    __shared__ int   hist[NCELL];               //  2 KB (then cursor)
    __shared__ int   wsum[NWAVE];
    __shared__ float wred[NWAVE];
    // total ~60.2 KB

    const int tid = threadIdx.x;
    const int s   = blockIdx.x / bps;
    const long segbase = (long)s * seg;

    // ---- phase 1: vectorized load of my 4 consecutive points, histogram ----
    if (tid < NCELL) hist[tid] = 0;
    __syncthreads();

    const float4* c4 = (const float4*)(coord + segbase * 3);   // 48KB*s: 16B aligned
    const float4 f0 = c4[tid*3 + 0];
    const float4 f1 = c4[tid*3 + 1];
    const float4 f2 = c4[tid*3 + 2];
    float px[PPT] = { f0.x, f0.w, f1.z, f2.y };
    float py[PPT] = { f0.y, f1.x, f1.w, f2.z };
    float pz[PPT] = { f0.z, f1.y, f2.x, f2.w };
    int   pc[PPT];
    #pragma unroll
    for (int k = 0; k < PPT; ++k) {
        pc[k] = cell_of(px[k], py[k], pz[k]);
        atomicAdd(&hist[pc[k]], 1);
    }
    __syncthreads();

    // ---- phase 2: exclusive scan of 512 cell counts (wave-shuffle) ----
    int own = 0;
    if (tid < NCELL) own = hist[tid];
    int v = own;
    #pragma unroll
    for (int off = 1; off < 64; off <<= 1) {
        const int t = __shfl_up(v, off);
        if ((tid & 63) >= off) v += t;
    }
    if ((tid & 63) == 63) wsum[tid >> 6] = v;
    __syncthreads();
    if (tid < 64) {                              // wave 0 scans the wave sums
        int w = (tid < NCELL / 64) ? wsum[tid] : 0;
        #pragma unroll
        for (int off = 1; off < NCELL / 64; off <<= 1) {
            const int t = __shfl_up(w, off);
            if (tid >= off) w += t;
        }
        if (tid < NCELL / 64) wsum[tid] = w;
    }
    __syncthreads();
    if (tid < NCELL) {
        const int wid  = tid >> 6;
        const int incl = v + (wid ? wsum[wid - 1] : 0);
        const int excl = incl - own;
        csl[tid] = excl;
        if (tid == NCELL - 1) csl[NCELL] = incl; // == seg
        hist[tid] = excl;                        // becomes scatter cursor
    }
    __syncthreads();

    // ---- phase 3: scatter into cell-sorted LDS ----
    #pragma unroll
    for (int k = 0; k < PPT; ++k) {
        const int slot = atomicAdd(&hist[pc[k]], 1);
        sxy[slot] = make_float2(px[k], py[k]);
        sz[slot]  = pz[k];
        sid[slot] = (unsigned short)(tid * PPT + k);
    }
    __syncthreads();

    // ---- phase 4: exact 3-NN for my 128 ORIGINAL points (8 lanes/point) ----
    const int sub   = tid & (SPLIT - 1);
    const int grp   = tid >> 3;
    const int jloc  = (blockIdx.x % bps) * PTS_PER_BLOCK + grp;  // original local idx
    const float mx = coord[(segbase + jloc)*3 + 0];              // 8-lane broadcast
    const float my = coord[(segbase + jloc)*3 + 1];
    const float mz = coord[(segbase + jloc)*3 + 2];
    int cx = (int)(mx * INV_CS); cx = cx > G-1 ? G-1 : cx;
    int cy = (int)(my * INV_CS); cy = cy > G-1 ? G-1 : cy;
    int cz = (int)(mz * INV_CS); cz = cz > G-1 ? G-1 : cz;

    unsigned m0, m1, m2, m3;
    int R = 1;
    for (;;) {
        m0 = BIGK; m1 = BIGK; m2 = BIGK; m3 = BIGK;
        const int x0 = max(cx - R, 0), x1 = min(cx + R, G-1);
        const int y0 = max(cy - R, 0), y1 = min(cy + R, G-1);
        const int z0 = max(cz - R, 0), z1 = min(cz + R, G-1);
        for (int gx = x0; gx <= x1; ++gx) {
            for (int gy = y0; gy <= y1; ++gy) {
                const int base = (gx << 6) | (gy << 3);
                const int q0 = csl[base + z0];
                const int q1 = csl[base + z1 + 1];
                for (int q = q0 + sub; q < q1; q += SPLIT) {
                    const float2 xy = sxy[q];
                    const float  zz = sz[q];
                    const float dx = mx - xy.x;
                    const float dy = my - xy.y;
                    const float dz = mz - zz;
                    const float d2 = fmaf(dx, dx, fmaf(dy, dy, dz * dz));
                    const unsigned key = (__float_as_uint(d2) & KEYMASK) | (unsigned)q;
                    pk_insert4(key, m0, m1, m2, m3);
                }
            }
        }
        // drop the self entry (key < 4096 iff d2trunc == 0 iff self):
        // exactly one lane in the group has it, at m0 (global min for that lane)
        if (m0 < 4096u) { m0 = m1; m1 = m2; m2 = m3; }
        // butterfly merge top-3 across the 8 lanes of this point
        #pragma unroll
        for (int mask = 1; mask < SPLIT; mask <<= 1) {
            const unsigned o0 = __shfl_xor(m0, mask);
            const unsigned o1 = __shfl_xor(m1, mask);
            const unsigned o2 = __shfl_xor(m2, mask);
            pk_insert(o0, m0, m1, m2);
            pk_insert(o1, m0, m1, m2);
            pk_insert(o2, m0, m1, m2);
        }
        // guard: truncated d3 underestimates true d3 by <= 2^-11 rel; 0.999
        // safety factor keeps the box-coverage proof valid.
        const float d3 = __uint_as_float(m2 & KEYMASK);
        const float g = (float)R * CS;
        if (d3 <= g * g * 0.999f || R >= G) break;
        ++R;   // exactness guard failed (rare boundary case) — widen box
    }

    // ---- epilogue: lanes sub=0,1,2 each handle one neighbor ----
    float loss = 0.0f;
    if (sub < KNN) {
        const unsigned mk = (sub == 0) ? m0 : (sub == 1) ? m1 : m2;
        const int nslot = (int)(mk & 0xFFFu);
        const int nk = (int)sid[nslot];                       // slot -> orig id
        const long gp = segbase + jloc;
        const float ppx = pred[gp*3+0], ppy = pred[gp*3+1], ppz = pred[gp*3+2];
        const float inp = sqrtf(ppx*ppx + ppy*ppy + ppz*ppz + 1e-8f) + 1e-10f;
        const float qx = ppx / inp, qy = ppy / inp, qz = ppz / inp;
        const float tx = target[gp*3+0], ty = target[gp*3+1], tz = target[gp*3+2];

        const long gn = segbase + nk;
        const float nx = pred[gn*3+0], ny = pred[gn*3+1], nz = pred[gn*3+2];
        const float ninp = sqrtf(nx*nx + ny*ny + nz*nz + 1e-8f) + 1e-10f;
        float sim = fabsf((nx*qx + ny*qy + nz*qz) / ninp);
        sim = fminf(sim, 1.0f);
        const float ux = target[gn*3+0], uy = target[gn*3+1], uz = target[gn*3+2];
        float tsim = fabsf(ux*tx + uy*ty + uz*tz);
        tsim = fminf(tsim, 1.0f);
        const float diff = sim - tsim;
        loss = diff * diff;
    }

    // wave reduce -> LDS -> one atomic per block
    #pragma unroll
    for (int off = 32; off > 0; off >>= 1)
        loss += __shfl_down(loss, off);
    if ((tid & 63) == 0) wred[tid >> 6] = loss;
    __syncthreads();
    if (tid == 0) {
        float ssum = 0.0f;
        #pragma unroll
        for (int w = 0; w < NWAVE; ++w) ssum += wred[w];
        atomicAdd(out, ssum * inv_total);
    }
}

extern "C" void kernel_launch(void* const* d_in, const int* in_sizes, int n_in,
                              void* d_out, int out_size, void* d_ws, size_t ws_size,
                              hipStream_t stream) {
    const float* pred   = (const float*)d_in[0];
    const float* coord  = (const float*)d_in[1];
    const float* target = (const float*)d_in[2];
    float* out = (float*)d_out;

    const int N    = in_sizes[0] / 3;
    const int nseg = in_sizes[3];
    const int seg  = N / nseg;                  // 4096
    const int bps  = seg / PTS_PER_BLOCK;       // 32

    hipMemsetAsync(out, 0, sizeof(float), stream);

    const float inv_total = 1.0f / ((float)nseg * (float)seg * (float)KNN);
    fused_knn_loss<<<N / PTS_PER_BLOCK, BLOCK, 0, stream>>>(
        pred, coord, target, out, seg, bps, inv_total);
}